// Round 2
// baseline (2344.561 us; speedup 1.0000x reference)
//
#include <hip/hip_runtime.h>
#include <hip/hip_bf16.h>

typedef __hip_bfloat16 bf16;

__device__ __forceinline__ float b2f(const bf16 v){ return __bfloat162float(v); }
__device__ __forceinline__ float ld(const float* p, long i){ return p[i]; }
__device__ __forceinline__ float ld(const bf16*  p, long i){ return b2f(p[i]); }

// ---- converted-params block offsets (floats) within P ----
#define OFF_C1W   0        /* 11616 */
#define OFF_C1B   11616    /* 32   */
#define OFF_RLG   11648    /* 2048 */
#define OFF_RLB   13696
#define OFF_RLM   15744
#define OFF_RLV   17792
#define OFF_RLCW  19840    /* 589824 */
#define OFF_RLCB  609664   /* 2048 */
#define OFF_BNG   611712
#define OFF_BNB   611744
#define OFF_BNM   611776
#define OFF_BNV   611808
#define OFF_C2W   611840   /* 32768 */
#define OFF_C2B   644608
#define OFF_C3W   644624   /* 16384 */
#define OFF_C3B   661008
#define OFF_C4W   661024   /* 9216 */
#define OFF_C4B   670240
#define OFF_C5W   670256   /* 6400 */
#define OFF_C5B   676656
#define OFF_F1B   676672   /* 4096 */
#define OFF_F2B   680768   /* 2048 */
#define OFF_F3B   682816   /* 24   */
#define P_TOTAL   682840

// ---------- dtype sniff: flag=1 if inputs are float32, 0 if bf16 ----------
// Reads x as bf16 at EVEN indices. If the buffer is f32, even bf16 slots are the
// low mantissa halves of floats -> random exponents -> mostly implausible magnitudes.
// If the buffer is bf16 (x ~ N(0,1)), all magnitudes are plausible.
__global__ void k_sniff(const void* __restrict__ x, int* __restrict__ flag)
{
    const bf16* xb = (const bf16*)x;
    const float v = fabsf(b2f(xb[2*threadIdx.x]));
    const int ok = (v >= 1e-6f && v <= 1e6f) ? 1 : 0;  // NaN compares false -> 0
    __shared__ int cnt;
    if (threadIdx.x == 0) cnt = 0;
    __syncthreads();
    atomicAdd(&cnt, ok);
    __syncthreads();
    if (threadIdx.x == 0) *flag = (cnt >= 192) ? 0 : 1;
}

// ---------- convert small params to f32 block P ----------
struct CvtArgs { const void* src[23]; int off[23]; int total; };

__global__ __launch_bounds__(256) void k_cvt(CvtArgs a, const int* __restrict__ flag,
                                             float* __restrict__ dst)
{
    const bool isf = (*flag != 0);
    for (int idx = blockIdx.x*256 + threadIdx.x; idx < a.total; idx += gridDim.x*256){
        int k = 0;
        #pragma unroll
        for (int j = 1; j < 23; j++) if (idx >= a.off[j]) k = j;
        const int e = idx - a.off[k];
        dst[idx] = isf ? ((const float*)a.src[k])[e] : b2f(((const bf16*)a.src[k])[e]);
    }
}

// ---------------- conv1: x[32,3,170,170] -> [32,32,160,160], k=11, pad 0 ----------------
template<typename T>
__device__ __forceinline__ void conv1_core(const T* __restrict__ x, const float* __restrict__ wl,
        const float bv, const int b, const int y, const int x0, float* __restrict__ op)
{
    float acc[8];
    #pragma unroll
    for (int j=0;j<8;j++) acc[j]=bv;
    for (int ci=0; ci<3; ci++){
        const float* wr = &wl[ci*121];
        #pragma unroll 1
        for (int ky=0; ky<11; ky++){
            const T* ip = x + ((long)(b*3+ci)*170 + (y+ky))*170 + x0;
            float v[18];
            #pragma unroll
            for (int j=0;j<18;j++) v[j] = ld(ip, j);
            #pragma unroll
            for (int kx=0;kx<11;kx++){
                const float wv = wr[ky*11+kx];
                #pragma unroll
                for (int j=0;j<8;j++) acc[j] = fmaf(v[j+kx], wv, acc[j]);
            }
        }
    }
    #pragma unroll
    for (int j=0;j<8;j++) op[j] = acc[j];
}

__global__ __launch_bounds__(256) void k_conv1(const void* __restrict__ x,
        const int* __restrict__ flag, const float* __restrict__ P, float* __restrict__ out)
{
    __shared__ float wl[363];
    const int co = blockIdx.y, b = blockIdx.z;
    for (int j = threadIdx.x; j < 363; j += 256) wl[j] = P[OFF_C1W + co*363 + j];
    __syncthreads();
    const int i = blockIdx.x*256 + threadIdx.x;
    if (i >= 3200) return;                 // 160 rows * 20 groups of 8
    const int y = i / 20, x0 = (i % 20) * 8;
    const float bv = P[OFF_C1B + co];
    float* op = out + (((long)b*32+co)*160 + y)*160 + x0;
    if (*flag) conv1_core<float>((const float*)x, wl, bv, b, y, x0, op);
    else       conv1_core<bf16 >((const bf16 *)x, wl, bv, b, y, x0, op);
}

// ------- region layer fused with relu+maxpool2+bn: in[32,32,160,160] -> pooled[32,32,80,80] -------
__global__ __launch_bounds__(256) void k_region_pool(const float* __restrict__ in,
        const float* __restrict__ P, float* __restrict__ pooled)
{
    __shared__ float s[32*22*22];          // zero-padded BN+ReLU patch, 61,952 B
    __shared__ float sc[32], sh[32];
    const int t = threadIdx.x;
    const int kk = blockIdx.x >> 5, b = blockIdx.x & 31;
    const int gi = kk >> 3, gj = kk & 7;
    const int net = gj * (gi + 1);         // idx = ii*jj + jj
    const int base = (b*32*160 + gi*20)*160 + gj*20;
    for (int j=t; j<32*22*22; j+=256) s[j] = 0.f;
    if (t < 32){
        const float inv = rsqrtf(P[OFF_RLV + net*32+t] + 1e-5f) * P[OFF_RLG + net*32+t];
        sc[t] = inv;
        sh[t] = P[OFF_RLB + net*32+t] - P[OFF_RLM + net*32+t] * inv;
    }
    __syncthreads();
    for (int e=t; e<12800; e+=256){
        const int c = e/400, rem = e%400, r = rem/20, col = rem%20;
        const float v = in[base + c*25600 + r*160 + col];
        s[c*484 + (r+1)*22 + (col+1)] = fmaxf(fmaf(v, sc[c], sh[c]), 0.f);
    }
    __syncthreads();
    float res[10][5];
    const float* wnet = P + OFF_RLCW + net*9216;
    #pragma unroll
    for (int it=0; it<10; it++){
        const int g = t + it*256;
        const int c = g/80, rem = g%80, r = rem/4, col0 = (rem%4)*5;
        float a0,a1,a2,a3,a4;
        a0=a1=a2=a3=a4=P[OFF_RLCB + net*32+c];
        const float* wc = wnet + c*288;
        #pragma unroll 1
        for (int ci=0; ci<32; ci++){
            const float* srow = &s[ci*484 + r*22 + col0];
            const float* wp = wc + ci*9;
            #pragma unroll
            for (int ky=0; ky<3; ky++){
                const float* sp = srow + ky*22;
                const float r0=sp[0],r1=sp[1],r2=sp[2],r3=sp[3],r4=sp[4],r5=sp[5],r6=sp[6];
                const float w0=wp[ky*3+0], w1=wp[ky*3+1], w2=wp[ky*3+2];
                a0 = fmaf(r2,w2,fmaf(r1,w1,fmaf(r0,w0,a0)));
                a1 = fmaf(r3,w2,fmaf(r2,w1,fmaf(r1,w0,a1)));
                a2 = fmaf(r4,w2,fmaf(r3,w1,fmaf(r2,w0,a2)));
                a3 = fmaf(r5,w2,fmaf(r4,w1,fmaf(r3,w0,a3)));
                a4 = fmaf(r6,w2,fmaf(r5,w1,fmaf(r4,w0,a4)));
            }
        }
        const int ob = base + c*25600 + r*160 + col0;   // residual add
        res[it][0] = a0 + in[ob+0];
        res[it][1] = a1 + in[ob+1];
        res[it][2] = a2 + in[ob+2];
        res[it][3] = a3 + in[ob+3];
        res[it][4] = a4 + in[ob+4];
    }
    __syncthreads();                        // reuse s as [32][20][20]
    #pragma unroll
    for (int it=0; it<10; it++){
        const int g = t + it*256;
        const int c = g/80, rem = g%80, r = rem/4, col0 = (rem%4)*5;
        float* sp = &s[c*400 + r*20 + col0];
        sp[0]=res[it][0]; sp[1]=res[it][1]; sp[2]=res[it][2]; sp[3]=res[it][3]; sp[4]=res[it][4];
    }
    __syncthreads();
    for (int e=t; e<3200; e+=256){          // relu -> 2x2 maxpool -> bn
        const int c = e/100, rem = e%100, pr = rem/10, pc = rem%10;
        const float* sp = &s[c*400 + (2*pr)*20 + 2*pc];
        float m = fmaxf(fmaxf(sp[0],sp[1]), fmaxf(sp[20],sp[21]));
        m = fmaxf(m, 0.f);
        const float inv = rsqrtf(P[OFF_BNV + c] + 1e-5f) * P[OFF_BNG + c];
        pooled[((b*32+c)*80 + gi*10+pr)*80 + gj*10+pc] =
            fmaf(m - P[OFF_BNM + c], inv, P[OFF_BNB + c]);
    }
}

// ---------------- generic direct conv (+relu), 8-wide register blocking ----------------
template<int CIN, int COUT, int KS, int STRIDE, int HIN, int WIN, int HOUT, int WOUT, int NG>
__global__ __launch_bounds__(256) void k_convN(const float* __restrict__ in,
        const float* __restrict__ w, const float* __restrict__ bias, float* __restrict__ out)
{
    __shared__ float wl[CIN*KS*KS];
    const int co = blockIdx.y, b = blockIdx.z;
    for (int j=threadIdx.x; j<CIN*KS*KS; j+=blockDim.x) wl[j] = w[co*CIN*KS*KS + j];
    __syncthreads();
    const int i = blockIdx.x*blockDim.x + threadIdx.x;
    if (i >= HOUT*NG) return;
    const int y = i / NG, x0 = (i % NG) * 8;
    float acc[8];
    const float bv = bias[co];
    #pragma unroll
    for (int j=0;j<8;j++) acc[j]=bv;
    constexpr int SPAN = STRIDE*7 + KS;
    for (int ci=0; ci<CIN; ci++){
        #pragma unroll 1
        for (int ky=0; ky<KS; ky++){
            const float* ip = in + ((b*CIN+ci)*HIN + (STRIDE*y+ky))*WIN + STRIDE*x0;
            float v[SPAN];
            #pragma unroll
            for (int j=0;j<SPAN;j++) v[j]=ip[j];   // tail over-read stays in ws; discarded
            const float* wr = &wl[(ci*KS+ky)*KS];
            #pragma unroll
            for (int kx=0;kx<KS;kx++){
                const float wv = wr[kx];
                #pragma unroll
                for (int j=0;j<8;j++) acc[j] = fmaf(v[STRIDE*j+kx], wv, acc[j]);
            }
        }
    }
    float* op = out + ((b*COUT+co)*HOUT + y)*WOUT + x0;
    #pragma unroll
    for (int j=0;j<8;j++){
        if (x0 + j < WOUT) op[j] = fmaxf(acc[j], 0.f);
    }
}

// ---------------- FC: y[32,N] = (relu)(x[32,K] @ w[N,K]^T + b), 2 outputs / block ----------------
template<typename T>
__device__ __forceinline__ void fc_dot(const float* __restrict__ x, const T* __restrict__ w,
        const int K, const int o0, float* acc0, float* acc1)
{
    const T* w0 = w + (long)o0*K;
    const T* w1 = w0 + K;
    for (int k=threadIdx.x; k<K; k+=256){
        const float wv0=ld(w0,k), wv1=ld(w1,k);
        #pragma unroll
        for (int b=0;b<32;b++){
            const float xv = x[b*K+k];
            acc0[b]=fmaf(xv,wv0,acc0[b]);
            acc1[b]=fmaf(xv,wv1,acc1[b]);
        }
    }
}

__global__ __launch_bounds__(256) void k_fc(const float* __restrict__ x,
        const void* __restrict__ w, const float* __restrict__ bias,
        const int* __restrict__ flag, float* __restrict__ y, int K, int N, int do_relu)
{
    const int t = threadIdx.x;
    const int o0 = blockIdx.x*2, o1 = o0+1;
    float acc0[32], acc1[32];
    #pragma unroll
    for (int b=0;b<32;b++){ acc0[b]=0.f; acc1[b]=0.f; }
    if (*flag) fc_dot<float>(x, (const float*)w, K, o0, acc0, acc1);
    else       fc_dot<bf16 >(x, (const bf16 *)w, K, o0, acc0, acc1);
    __shared__ float p0[4][32], p1[4][32];
    const int wave = t>>6, lane = t&63;
    #pragma unroll
    for (int b=0;b<32;b++){
        float v0=acc0[b], v1=acc1[b];
        #pragma unroll
        for (int off=32; off>0; off>>=1){
            v0 += __shfl_down(v0, off, 64);
            v1 += __shfl_down(v1, off, 64);
        }
        if (lane==0){ p0[wave][b]=v0; p1[wave][b]=v1; }
    }
    __syncthreads();
    if (t < 32){
        float s0 = p0[0][t]+p0[1][t]+p0[2][t]+p0[3][t] + bias[o0];
        float s1 = p1[0][t]+p1[1][t]+p1[2][t]+p1[3][t] + bias[o1];
        if (do_relu){ s0=fmaxf(s0,0.f); s1=fmaxf(s1,0.f); }
        y[t*N+o0]=s0; y[t*N+o1]=s1;
    }
}

// ---------------- paired log_softmax over axis 1 of [32,2,12] ----------------
__global__ void k_lsm(const float* __restrict__ in, const int* __restrict__ flag,
                      void* __restrict__ out)
{
    const int i = threadIdx.x;
    if (i >= 384) return;
    const int b = i/12, au = i%12;
    const float a0 = in[b*24+au], a1 = in[b*24+12+au];
    const float m = fmaxf(a0,a1);
    const float lse = m + logf(expf(a0-m)+expf(a1-m));
    const float o0 = a0-lse, o1 = a1-lse;
    if (*flag){
        ((float*)out)[b*24+au]    = o0;
        ((float*)out)[b*24+12+au] = o1;
    } else {
        ((bf16*)out)[b*24+au]    = __float2bfloat16(o0);
        ((bf16*)out)[b*24+12+au] = __float2bfloat16(o1);
    }
}

extern "C" void kernel_launch(void* const* d_in, const int* in_sizes, int n_in,
                              void* d_out, int out_size, void* d_ws, size_t ws_size,
                              hipStream_t stream) {
    (void)in_sizes; (void)n_in; (void)out_size; (void)ws_size;
    const void* x = d_in[0];

    float* A = (float*)d_ws;               // 26,214,400 floats (conv1 out, then ping-pong)
    float* B = A + 26214400;               //  6,553,600 floats (pooled, then ping-pong)
    float* P = B + 6553600;                //  converted f32 params (P_TOTAL floats)
    int* flag = (int*)(P + P_TOTAL);       //  dtype flag; total ws use ~134 MB

    CvtArgs a;
    const int src_idx[23] = {1,2,3,4,5,6,7,8,9,10,11,12,13,14,15,16,17,18,19,20,22,24,26};
    const int offs[23] = {OFF_C1W,OFF_C1B,OFF_RLG,OFF_RLB,OFF_RLM,OFF_RLV,OFF_RLCW,OFF_RLCB,
                          OFF_BNG,OFF_BNB,OFF_BNM,OFF_BNV,OFF_C2W,OFF_C2B,OFF_C3W,OFF_C3B,
                          OFF_C4W,OFF_C4B,OFF_C5W,OFF_C5B,OFF_F1B,OFF_F2B,OFF_F3B};
    for (int j=0;j<23;j++){ a.src[j] = d_in[src_idx[j]]; a.off[j] = offs[j]; }
    a.total = P_TOTAL;

    k_sniff<<<1,256,0,stream>>>(x, flag);
    k_cvt<<<(P_TOTAL+255)/256,256,0,stream>>>(a, flag, P);
    k_conv1<<<dim3(13,32,32),256,0,stream>>>(x, flag, P, A);
    k_region_pool<<<2048,256,0,stream>>>(A, P, B);
    // conv2: [32,32,80,80] -> [32,16,73,73]
    k_convN<32,16,8,1,80,80,73,73,10><<<dim3(3,16,32),256,0,stream>>>(B, P+OFF_C2W, P+OFF_C2B, A);
    // conv3: -> [32,16,66,66]
    k_convN<16,16,8,1,73,73,66,66,9><<<dim3(3,16,32),256,0,stream>>>(A, P+OFF_C3W, P+OFF_C3B, B);
    // conv4: stride 2 -> [32,16,31,31]
    k_convN<16,16,6,2,66,66,31,31,4><<<dim3(1,16,32),128,0,stream>>>(B, P+OFF_C4W, P+OFF_C4B, A);
    // conv5: -> [32,16,27,27]
    k_convN<16,16,5,1,31,31,27,27,4><<<dim3(1,16,32),128,0,stream>>>(A, P+OFF_C5W, P+OFF_C5B, B);
    // fc1: K=11664 -> 4096 (relu)
    k_fc<<<2048,256,0,stream>>>(B, d_in[21], P+OFF_F1B, flag, A, 11664, 4096, 1);
    // fc2: 4096 -> 2048 (relu)
    k_fc<<<1024,256,0,stream>>>(A, d_in[23], P+OFF_F2B, flag, B, 4096, 2048, 1);
    // fc3: 2048 -> 24
    k_fc<<<12,256,0,stream>>>(B, d_in[25], P+OFF_F3B, flag, A, 2048, 24, 0);
    k_lsm<<<1,384,0,stream>>>(A, flag, d_out);
}

// Round 3
// 1779.720 us; speedup vs baseline: 1.3174x; 1.3174x over previous
//
#include <hip/hip_runtime.h>
#include <hip/hip_bf16.h>

typedef __hip_bfloat16 bf16;

__device__ __forceinline__ float b2f(const bf16 v){ return __bfloat162float(v); }
__device__ __forceinline__ float ld(const float* p, long i){ return p[i]; }
__device__ __forceinline__ float ld(const bf16*  p, long i){ return b2f(p[i]); }

// ---- converted-params block offsets (floats) within P ----
#define OFF_C1W   0        /* 11616 */
#define OFF_C1B   11616    /* 32   */
#define OFF_RLG   11648    /* 2048 */
#define OFF_RLB   13696
#define OFF_RLM   15744
#define OFF_RLV   17792
#define OFF_RLCW  19840    /* 589824 slots: reused as bf16 WB [net][ci][tap][c] */
#define OFF_RLCB  609664   /* 2048 */
#define OFF_BNG   611712
#define OFF_BNB   611744
#define OFF_BNM   611776
#define OFF_BNV   611808
#define OFF_C2W   611840   /* 32768 */
#define OFF_C2B   644608
#define OFF_C3W   644624   /* 16384 */
#define OFF_C3B   661008
#define OFF_C4W   661024   /* 9216 */
#define OFF_C4B   670240
#define OFF_C5W   670256   /* 6400 */
#define OFF_C5B   676656
#define OFF_F1B   676672   /* 4096 */
#define OFF_F2B   680768   /* 2048 */
#define OFF_F3B   682816   /* 24   */
#define P_TOTAL   682840

// ---------- dtype sniff: flag=1 if inputs are float32, 0 if bf16 ----------
__global__ void k_sniff(const void* __restrict__ x, int* __restrict__ flag)
{
    const bf16* xb = (const bf16*)x;
    const float v = fabsf(b2f(xb[2*threadIdx.x]));
    const int ok = (v >= 1e-6f && v <= 1e6f) ? 1 : 0;
    __shared__ int cnt;
    if (threadIdx.x == 0) cnt = 0;
    __syncthreads();
    atomicAdd(&cnt, ok);
    __syncthreads();
    if (threadIdx.x == 0) *flag = (cnt >= 192) ? 0 : 1;
}

// ---------- convert params to f32 block P (+ bf16 transposed region weights WB) ----------
struct CvtArgs { const void* src[23]; int off[23]; const void* cw; int total; };

__global__ __launch_bounds__(256) void k_cvt(CvtArgs a, const int* __restrict__ flag,
                                             float* __restrict__ P)
{
    const bool isf = (*flag != 0);
    const int total2 = a.total + 589824;
    for (int idx = blockIdx.x*256 + threadIdx.x; idx < total2; idx += gridDim.x*256){
        if (idx < a.total){
            if (idx >= OFF_RLCW && idx < OFF_RLCB) continue;   // slot reused for WB
            int k = 0;
            #pragma unroll
            for (int j = 1; j < 23; j++) if (idx >= a.off[j]) k = j;
            const int e = idx - a.off[k];
            if (isf) P[idx] = ((const float*)a.src[k])[e];
            else     P[idx] = b2f(((const bf16*)a.src[k])[e]);
        } else {
            // WB[net][ci][tap][c] <- rl_cw[net][c][ci][tap], stored bf16
            const int d = idx - a.total;
            const int c = d & 31, q = d >> 5;
            const int tap = q % 9, r = q / 9;
            const int ci = r & 31, net = r >> 5;
            const long sidx = (long)((net*32 + c)*32 + ci)*9 + tap;
            float v;
            if (isf) v = ((const float*)a.cw)[sidx];
            else     v = b2f(((const bf16*)a.cw)[sidx]);
            ((bf16*)(P + OFF_RLCW))[d] = __float2bfloat16(v);
        }
    }
}

// ---------------- conv1 v2: x[32,3,170,170] -> [32,32,160,160], k=11 ----------------
// block=(rg 4-row group, b, co-half). LDS x-slab + f32 weights. thread=(co_l=t&15, xg=t>>4)
__global__ __launch_bounds__(256,3) void k_conv1(const void* __restrict__ x,
        const int* __restrict__ flag, const float* __restrict__ P, float* __restrict__ out)
{
    __shared__ float xs[3*14*176];     // 29,568 B
    __shared__ float wsm[363*16];      // 23,232 B  [tap][co16]
    const int t = threadIdx.x;
    const int rg = blockIdx.x, b = blockIdx.y, half = blockIdx.z;
    const int y0 = rg*4;
    for (int e=t; e<5808; e+=256){
        const int co_l = e & 15, tap = e >> 4;
        wsm[tap*16 + co_l] = P[OFF_C1W + (half*16+co_l)*363 + tap];
    }
    const bool isf = (*flag) != 0;
    if (isf){
        const float* xf = (const float*)x;
        for (int e=t; e<7140; e+=256){
            const int ci = e/2380, rem = e%2380, r = rem/170, col = rem%170;
            xs[(ci*14+r)*176 + col] = xf[((long)(b*3+ci)*170 + y0+r)*170 + col];
        }
    } else {
        const bf16* xf = (const bf16*)x;
        for (int e=t; e<7140; e+=256){
            const int ci = e/2380, rem = e%2380, r = rem/170, col = rem%170;
            xs[(ci*14+r)*176 + col] = b2f(xf[((long)(b*3+ci)*170 + y0+r)*170 + col]);
        }
    }
    __syncthreads();
    const int co_l = t & 15, xg = t >> 4;
    const int co = half*16 + co_l;
    float acc[4][10];
    const float bv = P[OFF_C1B + co];
    #pragma unroll
    for (int r=0;r<4;r++)
        #pragma unroll
        for (int j=0;j<10;j++) acc[r][j]=bv;
    for (int ci=0; ci<3; ci++){
        #pragma unroll 1
        for (int ir=0; ir<14; ir++){
            float xv[20];
            #pragma unroll
            for (int j=0;j<20;j++) xv[j] = xs[(ci*14+ir)*176 + xg*10 + j];
            const int rlo = (ir>10)? ir-10 : 0;
            const int rhi = (ir<3)? ir : 3;
            #pragma unroll
            for (int r=0;r<4;r++){
                if (r < rlo || r > rhi) continue;     // wave-uniform guard
                const int ky = ir - r;
                const float* wrow = &wsm[(ci*121 + ky*11)*16 + co_l];
                #pragma unroll
                for (int kx=0;kx<11;kx++){
                    const float wv = wrow[kx*16];
                    #pragma unroll
                    for (int j=0;j<10;j++) acc[r][j] = fmaf(xv[j+kx], wv, acc[r][j]);
                }
            }
        }
    }
    #pragma unroll
    for (int r=0;r<4;r++){
        float* op = out + (((long)b*32+co)*160 + y0+r)*160 + xg*10;
        #pragma unroll
        for (int j=0;j<10;j++) op[j] = acc[r][j];
    }
}

// ------- region layer fused relu+maxpool2+bn; block = (patch, batch, row-half) -------
__global__ __launch_bounds__(256,3) void k_region_pool(const float* __restrict__ in,
        const float* __restrict__ P, float* __restrict__ pooled)
{
    __shared__ float s[32*12*22];       // 33,792 B  [ci][row12][col22] (BN+ReLU, padded)
    __shared__ bf16  wsm[32*9*32];      // 18,432 B  [ci][tap][c]
    __shared__ float sc[32], sh[32];
    const int t = threadIdx.x;
    const int bx = blockIdx.x;
    const int h  = bx & 1;
    const int b  = (bx >> 1) & 31;
    const int kk = bx >> 6;
    const int gi = kk >> 3, gj = kk & 7;
    const int net = gj * (gi + 1);      // idx = ii*jj + jj
    const int ibase = (b*32*160 + gi*20)*160 + gj*20;
    { const uint* src = (const uint*)((const bf16*)(P + OFF_RLCW) + net*9216);
      uint* dst = (uint*)wsm;
      for (int j=t; j<4608; j+=256) dst[j] = src[j]; }
    if (t < 32){
        const float inv = rsqrtf(P[OFF_RLV + net*32+t] + 1e-5f) * P[OFF_RLG + net*32+t];
        sc[t] = inv;
        sh[t] = P[OFF_RLB + net*32+t] - P[OFF_RLM + net*32+t]*inv;
    }
    for (int j=t; j<8448; j+=256) s[j] = 0.f;
    __syncthreads();
    const int p0 = h*9, sr0 = 1-h;      // staged patch rows p0..p0+10 -> s rows sr0..sr0+10
    for (int e=t; e<7040; e+=256){
        const int ci = e/220, rem = e%220, rr = rem/20, col = rem%20;
        const float v = in[ibase + ci*25600 + (p0+rr)*160 + col];
        s[ci*264 + (sr0+rr)*22 + (col+1)] = fmaxf(fmaf(v, sc[ci], sh[ci]), 0.f);
    }
    __syncthreads();
    const int c = t & 31, tile = t >> 5;            // wave: 2 distinct tiles -> LDS broadcast
    const int r0 = (tile >> 2)*5, c0 = (tile & 3)*5;
    float acc[5][5];
    { const float bv = P[OFF_RLCB + net*32 + c];
      #pragma unroll
      for (int rr=0;rr<5;rr++)
          #pragma unroll
          for (int cc=0;cc<5;cc++) acc[rr][cc]=bv; }
    #pragma unroll 1
    for (int ci=0; ci<32; ci++){
        float win[7][7];
        const float* sp = &s[ci*264 + r0*22 + c0];
        #pragma unroll
        for (int i7=0;i7<7;i7++)
            #pragma unroll
            for (int j7=0;j7<7;j7++) win[i7][j7] = sp[i7*22+j7];
        float wv[9];
        const bf16* wp = &wsm[ci*288 + c];
        #pragma unroll
        for (int q=0;q<9;q++) wv[q] = b2f(wp[q*32]);
        #pragma unroll
        for (int rr=0;rr<5;rr++)
            #pragma unroll
            for (int dy=0;dy<3;dy++)
                #pragma unroll
                for (int dx=0;dx<3;dx++){
                    const float wq = wv[dy*3+dx];
                    #pragma unroll
                    for (int cc=0;cc<5;cc++)
                        acc[rr][cc] = fmaf(win[rr+dy][cc+dx], wq, acc[rr][cc]);
                }
    }
    __syncthreads();                    // all conv reads of s done
    {   // residual add, write res to s as [c][10][20]
        const int obase = ibase + c*25600 + (h*10 + r0)*160 + c0;
        #pragma unroll
        for (int rr=0;rr<5;rr++)
            #pragma unroll
            for (int cc=0;cc<5;cc++)
                s[c*200 + (r0+rr)*20 + (c0+cc)] = acc[rr][cc] + in[obase + rr*160 + cc];
    }
    __syncthreads();
    for (int e=t; e<1600; e+=256){      // relu -> 2x2 maxpool -> bn
        const int c2 = e/50, rem = e%50, pr = rem/10, pc = rem%10;
        const float* sp = &s[c2*200 + (2*pr)*20 + 2*pc];
        float m = fmaxf(fmaxf(sp[0],sp[1]), fmaxf(sp[20],sp[21]));
        m = fmaxf(m, 0.f);
        const float inv = rsqrtf(P[OFF_BNV + c2] + 1e-5f) * P[OFF_BNG + c2];
        pooled[((b*32+c2)*80 + gi*10 + h*5 + pr)*80 + gj*10 + pc] =
            fmaf(m - P[OFF_BNM + c2], inv, P[OFF_BNB + c2]);
    }
}

// ------- conv2/conv3 v2: KS=8, COUT=16, 4 rows x 5 cols per thread, ci-chunked LDS -------
template<int CIN, int HIN, int WIN, int HOUT, int WOUT>
__global__ __launch_bounds__(256,2) void k_convB(const float* __restrict__ in,
        const float* __restrict__ w, const float* __restrict__ bias, float* __restrict__ out)
{
    constexpr int KS = 8, CCH = 8, SSTR = 88;
    __shared__ float xs[CCH*11*SSTR];     // 30,976 B
    __shared__ float wsm[CCH*KS*KS*16];   // 32,768 B  [ci][tap][co16]
    const int t = threadIdx.x;
    const int rg = blockIdx.x, b = blockIdx.y;
    const int y0 = rg*4;
    const int co_l = t & 15, xg = t >> 4;
    float acc[4][5];
    { const float bv = bias[co_l];
      #pragma unroll
      for (int r=0;r<4;r++)
          #pragma unroll
          for (int j=0;j<5;j++) acc[r][j]=bv; }
    for (int ch=0; ch<CIN/CCH; ch++){
        for (int e=t; e<CCH*11*SSTR; e+=256){
            const int col = e % SSTR, r = (e/SSTR)%11, ci = e/(11*SSTR);
            int row = y0 + r; if (row > HIN-1) row = HIN-1;
            xs[e] = (col < WIN) ? in[((long)(b*CIN + ch*CCH + ci)*HIN + row)*WIN + col] : 0.f;
        }
        for (int e=t; e<CCH*64*16; e+=256){
            const int cl = e & 15, rest = e >> 4;
            const int tap = rest & 63, ci = rest >> 6;
            wsm[(ci*64 + tap)*16 + cl] = w[((long)cl*CIN + ch*CCH + ci)*64 + tap];
        }
        __syncthreads();
        for (int ci=0; ci<CCH; ci++){
            #pragma unroll 1
            for (int ir=0; ir<11; ir++){
                float xv[12];
                #pragma unroll
                for (int j=0;j<12;j++) xv[j] = xs[(ci*11+ir)*SSTR + xg*5 + j];
                const int rlo = (ir>7)? ir-7 : 0;
                const int rhi = (ir<3)? ir : 3;
                #pragma unroll
                for (int r=0;r<4;r++){
                    if (r < rlo || r > rhi) continue;
                    const int ky = ir - r;
                    const float* wrow = &wsm[(ci*64 + ky*8)*16 + co_l];
                    #pragma unroll
                    for (int kx=0;kx<8;kx++){
                        const float wv = wrow[kx*16];
                        #pragma unroll
                        for (int j=0;j<5;j++) acc[r][j] = fmaf(xv[j+kx], wv, acc[r][j]);
                    }
                }
            }
        }
        __syncthreads();
    }
    #pragma unroll
    for (int r=0;r<4;r++){
        if (y0 + r >= HOUT) continue;
        float* op = out + ((long)(b*16+co_l)*HOUT + y0+r)*WOUT;
        #pragma unroll
        for (int j=0;j<5;j++){
            const int col = xg*5 + j;
            if (col < WOUT) op[col] = fmaxf(acc[r][j], 0.f);
        }
    }
}

// ---------------- generic direct conv (+relu) for the small conv4/conv5 ----------------
template<int CIN, int COUT, int KS, int STRIDE, int HIN, int WIN, int HOUT, int WOUT, int NG>
__global__ __launch_bounds__(256) void k_convN(const float* __restrict__ in,
        const float* __restrict__ w, const float* __restrict__ bias, float* __restrict__ out)
{
    __shared__ float wl[CIN*KS*KS];
    const int co = blockIdx.y, b = blockIdx.z;
    for (int j=threadIdx.x; j<CIN*KS*KS; j+=blockDim.x) wl[j] = w[co*CIN*KS*KS + j];
    __syncthreads();
    const int i = blockIdx.x*blockDim.x + threadIdx.x;
    if (i >= HOUT*NG) return;
    const int y = i / NG, x0 = (i % NG) * 8;
    float acc[8];
    const float bv = bias[co];
    #pragma unroll
    for (int j=0;j<8;j++) acc[j]=bv;
    constexpr int SPAN = STRIDE*7 + KS;
    for (int ci=0; ci<CIN; ci++){
        #pragma unroll 1
        for (int ky=0; ky<KS; ky++){
            const float* ip = in + ((b*CIN+ci)*HIN + (STRIDE*y+ky))*WIN + STRIDE*x0;
            float v[SPAN];
            #pragma unroll
            for (int j=0;j<SPAN;j++) v[j]=ip[j];
            const float* wr = &wl[(ci*KS+ky)*KS];
            #pragma unroll
            for (int kx=0;kx<KS;kx++){
                const float wv = wr[kx];
                #pragma unroll
                for (int j=0;j<8;j++) acc[j] = fmaf(v[STRIDE*j+kx], wv, acc[j]);
            }
        }
    }
    float* op = out + ((b*COUT+co)*HOUT + y)*WOUT + x0;
    #pragma unroll
    for (int j=0;j<8;j++){
        if (x0 + j < WOUT) op[j] = fmaxf(acc[j], 0.f);
    }
}

// ---------------- FC: y[32,N] = (relu)(x[32,K] @ w[N,K]^T + b) ----------------
template<typename T>
__device__ __forceinline__ void fc_dot(const float* __restrict__ x, const T* __restrict__ w,
        const int K, const int o0, float* acc0, float* acc1)
{
    const T* w0 = w + (long)o0*K;
    const T* w1 = w0 + K;
    for (int k=threadIdx.x; k<K; k+=256){
        const float wv0=ld(w0,k), wv1=ld(w1,k);
        #pragma unroll
        for (int b=0;b<32;b++){
            const float xv = x[b*K+k];
            acc0[b]=fmaf(xv,wv0,acc0[b]);
            acc1[b]=fmaf(xv,wv1,acc1[b]);
        }
    }
}

__global__ __launch_bounds__(256) void k_fc(const float* __restrict__ x,
        const void* __restrict__ w, const float* __restrict__ bias,
        const int* __restrict__ flag, float* __restrict__ y, int K, int N, int do_relu)
{
    const int t = threadIdx.x;
    const int o0 = blockIdx.x*2, o1 = o0+1;
    float acc0[32], acc1[32];
    #pragma unroll
    for (int b=0;b<32;b++){ acc0[b]=0.f; acc1[b]=0.f; }
    if (*flag) fc_dot<float>(x, (const float*)w, K, o0, acc0, acc1);
    else       fc_dot<bf16 >(x, (const bf16 *)w, K, o0, acc0, acc1);
    __shared__ float p0[4][32], p1[4][32];
    const int wave = t>>6, lane = t&63;
    #pragma unroll
    for (int b=0;b<32;b++){
        float v0=acc0[b], v1=acc1[b];
        #pragma unroll
        for (int off=32; off>0; off>>=1){
            v0 += __shfl_down(v0, off, 64);
            v1 += __shfl_down(v1, off, 64);
        }
        if (lane==0){ p0[wave][b]=v0; p1[wave][b]=v1; }
    }
    __syncthreads();
    if (t < 32){
        float s0 = p0[0][t]+p0[1][t]+p0[2][t]+p0[3][t] + bias[o0];
        float s1 = p1[0][t]+p1[1][t]+p1[2][t]+p1[3][t] + bias[o1];
        if (do_relu){ s0=fmaxf(s0,0.f); s1=fmaxf(s1,0.f); }
        y[t*N+o0]=s0; y[t*N+o1]=s1;
    }
}

// ---------------- paired log_softmax over axis 1 of [32,2,12] ----------------
__global__ void k_lsm(const float* __restrict__ in, const int* __restrict__ flag,
                      void* __restrict__ out)
{
    const int i = threadIdx.x;
    if (i >= 384) return;
    const int b = i/12, au = i%12;
    const float a0 = in[b*24+au], a1 = in[b*24+12+au];
    const float m = fmaxf(a0,a1);
    const float lse = m + logf(expf(a0-m)+expf(a1-m));
    const float o0 = a0-lse, o1 = a1-lse;
    if (*flag){
        ((float*)out)[b*24+au]    = o0;
        ((float*)out)[b*24+12+au] = o1;
    } else {
        ((bf16*)out)[b*24+au]    = __float2bfloat16(o0);
        ((bf16*)out)[b*24+12+au] = __float2bfloat16(o1);
    }
}

extern "C" void kernel_launch(void* const* d_in, const int* in_sizes, int n_in,
                              void* d_out, int out_size, void* d_ws, size_t ws_size,
                              hipStream_t stream) {
    (void)in_sizes; (void)n_in; (void)out_size; (void)ws_size;
    const void* x = d_in[0];

    float* A = (float*)d_ws;               // 26,214,400 floats
    float* B = A + 26214400;               //  6,553,600 floats
    float* P = B + 6553600;                //  P_TOTAL floats (WB lives in rl_cw slot)
    int* flag = (int*)(P + P_TOTAL);

    CvtArgs a;
    const int src_idx[23] = {1,2,3,4,5,6,7,8,9,10,11,12,13,14,15,16,17,18,19,20,22,24,26};
    const int offs[23] = {OFF_C1W,OFF_C1B,OFF_RLG,OFF_RLB,OFF_RLM,OFF_RLV,OFF_RLCW,OFF_RLCB,
                          OFF_BNG,OFF_BNB,OFF_BNM,OFF_BNV,OFF_C2W,OFF_C2B,OFF_C3W,OFF_C3B,
                          OFF_C4W,OFF_C4B,OFF_C5W,OFF_C5B,OFF_F1B,OFF_F2B,OFF_F3B};
    for (int j=0;j<23;j++){ a.src[j] = d_in[src_idx[j]]; a.off[j] = offs[j]; }
    a.cw = d_in[7];
    a.total = P_TOTAL;

    k_sniff<<<1,256,0,stream>>>(x, flag);
    k_cvt<<<(P_TOTAL+589824+255)/256,256,0,stream>>>(a, flag, P);
    k_conv1<<<dim3(40,32,2),256,0,stream>>>(x, flag, P, A);
    k_region_pool<<<4096,256,0,stream>>>(A, P, B);
    // conv2: [32,32,80,80] -> [32,16,73,73]
    k_convB<32,80,80,73,73><<<dim3(19,32),256,0,stream>>>(B, P+OFF_C2W, P+OFF_C2B, A);
    // conv3: -> [32,16,66,66]
    k_convB<16,73,73,66,66><<<dim3(17,32),256,0,stream>>>(A, P+OFF_C3W, P+OFF_C3B, B);
    // conv4: stride 2 -> [32,16,31,31]
    k_convN<16,16,6,2,66,66,31,31,4><<<dim3(1,16,32),128,0,stream>>>(B, P+OFF_C4W, P+OFF_C4B, A);
    // conv5: -> [32,16,27,27]
    k_convN<16,16,5,1,31,31,27,27,4><<<dim3(1,16,32),128,0,stream>>>(A, P+OFF_C5W, P+OFF_C5B, B);
    // fc1: K=11664 -> 4096 (relu)
    k_fc<<<2048,256,0,stream>>>(B, d_in[21], P+OFF_F1B, flag, A, 11664, 4096, 1);
    // fc2: 4096 -> 2048 (relu)
    k_fc<<<1024,256,0,stream>>>(A, d_in[23], P+OFF_F2B, flag, B, 4096, 2048, 1);
    // fc3: 2048 -> 24
    k_fc<<<12,256,0,stream>>>(B, d_in[25], P+OFF_F3B, flag, A, 2048, 24, 0);
    k_lsm<<<1,384,0,stream>>>(A, flag, d_out);
}